// Round 20
// baseline (303.542 us; speedup 1.0000x reference)
//
#include <hip/hip_runtime.h>

// FrequencyAwareSpatialAttention via MFMA.
// R20: 16-wave blocks (NT=1024) — halve the per-wave serial chain AND hit
// the 2048-thread/CU hardware occupancy cap (2 blocks x 1024 = 32 waves/CU
// vs 24 before). Each wave owns ONE pair-set: 34 loads + 17 sobel iters
// (half of R19). W-fragments move to LDS (wlds, copied once per block) so
// the MFMA phase needs ~30 live regs instead of 72+ — the R13/R15 spill
// trap at the 64-reg budget is structurally avoided.
// Carried over (validated): asm GLD clusters + vmcnt, f16 packed separable
// sobel + DPP, swizzled padded frq, f16 MFMA, XCD-chunked swizzle.

#define WSZ 17
#define PS  19            // padded 17+2
#define PSS (PS * PS)     // 361
#define NT  1024          // 16 waves
#define CH  (510 * 510)   // floats per channel plane

typedef __attribute__((ext_vector_type(8))) _Float16 f16x8;
typedef __attribute__((ext_vector_type(2))) _Float16 f16x2;
typedef __attribute__((ext_vector_type(4))) float f32x4;
typedef __attribute__((ext_vector_type(2))) float f32x2;

// XOR swizzle: involution within each 128B frq row (row = padded pixel).
__device__ __forceinline__ int swz(int off) {
    return off ^ (((off >> 7) & 7) << 4);
}

__device__ __forceinline__ unsigned short f2h(float f) {
    _Float16 h = (_Float16)f;                 // RNE
    unsigned short u;
    __builtin_memcpy(&u, &h, 2);
    return u;
}

// v_cvt_pkrtz_f16_f32: pack two f32 -> one reg of 2 halves (bit-cast type)
__device__ __forceinline__ f16x2 pkrtz(float a, float b) {
    auto r = __builtin_amdgcn_cvt_pkrtz(a, b);
    f16x2 o;
    __builtin_memcpy(&o, &r, 4);
    return o;
}

// lane i <- lane i-1 (wave_shr:1), lane 0 <- 0
__device__ __forceinline__ int dpp_shr1_i(int v) {
    return __builtin_amdgcn_update_dpp(0, v, 0x138, 0xf, 0xf, true);
}
// lane i <- lane i+1 (wave_shl:1), lane 63 <- 0
__device__ __forceinline__ int dpp_shl1_i(int v) {
    return __builtin_amdgcn_update_dpp(0, v, 0x130, 0xf, 0xf, true);
}
__device__ __forceinline__ float dpp_shr1(float v) {
    return __int_as_float(dpp_shr1_i(__float_as_int(v)));
}
__device__ __forceinline__ float dpp_shl1(float v) {
    return __int_as_float(dpp_shl1_i(__float_as_int(v)));
}

// 8 forced-depth loads: rows 2k,2k+1 at voff k via offset:0/2040 immediates.
#define GLD8(d0,d1,d2,d3,d4,d5,d6,d7, o0,o1,o2,o3, sp)      \
    asm volatile(                                            \
        "global_load_dword %0, %8, %12\n\t"                  \
        "global_load_dword %1, %8, %12 offset:2040\n\t"      \
        "global_load_dword %2, %9, %12\n\t"                  \
        "global_load_dword %3, %9, %12 offset:2040\n\t"      \
        "global_load_dword %4, %10, %12\n\t"                 \
        "global_load_dword %5, %10, %12 offset:2040\n\t"     \
        "global_load_dword %6, %11, %12\n\t"                 \
        "global_load_dword %7, %11, %12 offset:2040\n\t"     \
        : "+v"(d0),"+v"(d1),"+v"(d2),"+v"(d3),               \
          "+v"(d4),"+v"(d5),"+v"(d6),"+v"(d7)                \
        : "v"(o0),"v"(o1),"v"(o2),"v"(o3),"s"(sp))

// 9 loads: rows 8..15 (pairs) + row 16.
#define GLD9(d0,d1,d2,d3,d4,d5,d6,d7,d8, o0,o1,o2,o3,o4, sp) \
    asm volatile(                                            \
        "global_load_dword %0, %9, %14\n\t"                  \
        "global_load_dword %1, %9, %14 offset:2040\n\t"      \
        "global_load_dword %2, %10, %14\n\t"                 \
        "global_load_dword %3, %10, %14 offset:2040\n\t"     \
        "global_load_dword %4, %11, %14\n\t"                 \
        "global_load_dword %5, %11, %14 offset:2040\n\t"     \
        "global_load_dword %6, %12, %14\n\t"                 \
        "global_load_dword %7, %12, %14 offset:2040\n\t"     \
        "global_load_dword %8, %13, %14\n\t"                 \
        : "+v"(d0),"+v"(d1),"+v"(d2),"+v"(d3),"+v"(d4),      \
          "+v"(d5),"+v"(d6),"+v"(d7),"+v"(d8)                \
        : "v"(o0),"v"(o1),"v"(o2),"v"(o3),"v"(o4),"s"(sp))

// Pre-kernel: transpose+convert w1 [16][64][3][3] fp32 into A-fragment order (f16).
// Fragment (dij, ks): lane l holds A[m = l&15][k = ks*32 + 8*(l>>4) + j], j=0..7.
__global__ void prep_w1(const float* __restrict__ w1, unsigned short* __restrict__ wt) {
    const int dij = blockIdx.x >> 1;
    const int ks  = blockIdx.x & 1;
    const int l   = threadIdx.x;           // 0..63
    const int m   = l & 15;
    const int kb  = ks * 32 + 8 * (l >> 4);
    unsigned short v[8];
#pragma unroll
    for (int jj = 0; jj < 8; ++jj)
        v[jj] = f2h(w1[m * 576 + (kb + jj) * 9 + dij]);
    f16x8 o;
    __builtin_memcpy(&o, v, 16);
    ((f16x8*)wt)[blockIdx.x * 64 + l] = o;
}

__global__ __launch_bounds__(NT, 8)
void fasa_mfma(const float* __restrict__ x,
               const float* __restrict__ sobel_w,
               const unsigned short* __restrict__ wt,
               const float* __restrict__ b1,
               const float* __restrict__ w2,
               const float* __restrict__ b2,
               float* __restrict__ out)
{
    __shared__ __align__(16) char frq[PSS * 128];   // 46208 B, [pp][c] f16 swizzled
    __shared__ __align__(16) char wlds[18432];      // W fragments (18 x 64 x 16B)
                                                    // total 64640 B -> 2 blocks/CU

    const int t    = threadIdx.x;
    const int lane = t & 63;
    const int wave = __builtin_amdgcn_readfirstlane(t >> 6);   // 0..15

    // XCD-chunked swizzle (bijective, 3600 = 8*450)
    const int bid = blockIdx.x;
    const int win = (bid & 7) * 450 + (bid >> 3);   // b*900 + wh*30 + ww
    const int b   = win / 900;
    const int rem = win % 900;
    const int h0  = (rem / 30) * WSZ;
    const int w0  = (rem % 30) * WSZ;

    // ---- zero the 72 border rows of frq (interior rows all get written) ----
    if (t < 72 * 8) {
        int r = t >> 3, k = t & 7;
        int row;
        if      (r < 19) row = r;                   // pi == 0
        else if (r < 38) row = 342 + (r - 19);      // pi == 18
        else if (r < 55) row = (r - 37) * PS;       // pj == 0, pi 1..17
        else             row = (r - 54) * PS + 18;  // pj == 18, pi 1..17
        *(f32x4*)(frq + row * 128 + k * 16) = (f32x4){0.f, 0.f, 0.f, 0.f};
    }

    // ---- sobel weights: ALL channels share one 3x3 (tiled in setup) ----
    const float sw0 = sobel_w[0], sw1 = sobel_w[1], sw2 = sobel_w[2];
    const float sw3 = sobel_w[3], sw4 = sobel_w[4], sw5 = sobel_w[5];
    const float sw6 = sobel_w[6], sw7 = sobel_w[7], sw8 = sobel_w[8];
    // separable fast path: middle column zero, col0 = -col2 (true for Sobel)
    const bool fast = (sw1 == 0.f) && (sw4 == 0.f) && (sw7 == 0.f) &&
                      (sw0 == -sw2) && (sw3 == -sw5) && (sw6 == -sw8);
    const f16x2 sw2h = {(_Float16)sw2, (_Float16)sw2};
    const f16x2 sw5h = {(_Float16)sw5, (_Float16)sw5};
    const f16x2 sw8h = {(_Float16)sw8, (_Float16)sw8};

    // ---- staging: lane = (grp, j); wave w owns pairs {2w, 2w+1} ----
    const int j   = lane & 31;       // column, active when j < 17
    const int grp = lane >> 5;       // which pair of this wave's two
    const bool jac = (j < 17);
    const int pr  = 2 * wave + grp;  // pair index 0..31

    // wave-uniform bases (channel 4*wave + 2*grp folded per-lane via voff)
    const float* sp0 = x + ((size_t)(b * 64 + 4 * wave)) * CH
                         + (size_t)h0 * 510 + w0;
    const float* sp1 = sp0 + (size_t)CH;          // odd channel of pair

    // per-lane voffsets: grp channel offset + column + row pairs (4080*k)
    const unsigned v0 = (unsigned)((grp * 2 * CH + j) * 4);
    const unsigned vk0 = v0,           vk1 = v0 + 4080u,  vk2 = v0 + 8160u;
    const unsigned vk3 = v0 + 12240u,  vk4 = v0 + 16320u, vk5 = v0 + 20400u;
    const unsigned vk6 = v0 + 24480u,  vk7 = v0 + 28560u, vk8 = v0 + 32640u;

    // data regs, pre-zeroed at full exec so inactive lanes (j>=17) keep the
    // zero columns the DPP edge handling relies on (lanes 17/31/49/63).
    float xA[17], yA[17];
#pragma unroll
    for (int i = 0; i < 17; ++i) { xA[i] = 0.f; yA[i] = 0.f; }

    if (jac) {
        GLD8(xA[0],xA[1],xA[2],xA[3],xA[4],xA[5],xA[6],xA[7], vk0,vk1,vk2,vk3, sp0);
        GLD9(xA[8],xA[9],xA[10],xA[11],xA[12],xA[13],xA[14],xA[15],xA[16],
             vk4,vk5,vk6,vk7,vk8, sp0);
        GLD8(yA[0],yA[1],yA[2],yA[3],yA[4],yA[5],yA[6],yA[7], vk0,vk1,vk2,vk3, sp1);
        GLD9(yA[8],yA[9],yA[10],yA[11],yA[12],yA[13],yA[14],yA[15],yA[16],
             vk4,vk5,vk6,vk7,vk8, sp1);
    }

    // ---- copy W fragments to LDS (18432 B = 1152 f32x4), overlaps loads ----
    {
        const f32x4* wsrc = (const f32x4*)wt;
        f32x4* wdst = (f32x4*)wlds;
        wdst[t] = wsrc[t];                       // t < 1024
        if (t < 128) wdst[1024 + t] = wsrc[1024 + t];
    }

    // epilogue constants (scalar-ish loads, overlap too)
    float b1v[4], w2v[4];
#pragma unroll
    for (int r = 0; r < 4; ++r) {
        int m = 4 * (lane >> 4) + r;
        b1v[r] = b1[m];
        w2v[r] = w2[m];
    }
    const float b2v = b2[0];

    asm volatile("s_waitcnt vmcnt(0)" ::: "memory");
    __builtin_amdgcn_sched_barrier(0);

    // ---- sobel: one pair-set per wave (17 iterations) ----
    const int pairOff = pr * 4;                  // pair byte offset in frq row
    if (fast) {
        f16x2 xh[17];
#pragma unroll
        for (int i = 0; i < 17; ++i)
            xh[i] = pkrtz(xA[i], yA[i]);
        const f16x2 zero = {(_Float16)0.f, (_Float16)0.f};
#pragma unroll
        for (int i = 0; i < 17; ++i) {
            f16x2 top = (i > 0)  ? xh[i - 1] : zero;
            f16x2 bot = (i < 16) ? xh[i + 1] : zero;
            f16x2 h = sw2h * top + sw5h * xh[i] + sw8h * bot;
            int hi;
            __builtin_memcpy(&hi, &h, 4);
            int sl = dpp_shl1_i(hi);
            int sr = dpp_shr1_i(hi);
            f16x2 hl, hr;
            __builtin_memcpy(&hl, &sl, 4);
            __builtin_memcpy(&hr, &sr, 4);
            f16x2 o = hl - hr;
            unsigned pkv;
            __builtin_memcpy(&pkv, &o, 4);
            if (jac)
                *(unsigned*)(frq + swz(((i + 1) * PS + (j + 1)) * 128 + pairOff)) = pkv;
        }
    } else {
#pragma unroll
        for (int i = 0; i < 17; ++i) {
            f32x2 top = { (i > 0  ? xA[i - 1] : 0.f), (i > 0  ? yA[i - 1] : 0.f) };
            f32x2 mid = { xA[i],                       yA[i] };
            f32x2 bot = { (i < 16 ? xA[i + 1] : 0.f), (i < 16 ? yA[i + 1] : 0.f) };
            f32x2 p0 = sw0 * top + sw3 * mid + sw6 * bot;
            f32x2 p1 = sw1 * top + sw4 * mid + sw7 * bot;
            f32x2 p2 = sw2 * top + sw5 * mid + sw8 * bot;
            f32x2 o;
            o.x = p1.x + dpp_shr1(p0.x) + dpp_shl1(p2.x);
            o.y = p1.y + dpp_shr1(p0.y) + dpp_shl1(p2.y);
            f16x2 oh = pkrtz(o.x, o.y);
            unsigned pkv;
            __builtin_memcpy(&pkv, &oh, 4);
            if (jac)
                *(unsigned*)(frq + swz(((i + 1) * PS + (j + 1)) * 128 + pairOff)) = pkv;
        }
    }

    __syncthreads();   // frq + wlds complete across waves

    // ---- conv1 via MFMA: wave w handles pixel tiles {w, w+16} ----
    const int n   = lane & 15;          // pixel within tile (MFMA N)
    const int g16 = (lane >> 4) * 16;   // 8-channel chunk byte offset
    const int DOFF[9] = {0, 1, 2, PS, PS + 1, PS + 2, 2 * PS, 2 * PS + 1, 2 * PS + 2};
    const char* wbase = wlds + lane * 16;   // fragment (d2) at + d2*1024

#pragma unroll 1
    for (int nt = wave; nt < 19; nt += 16) {
        int p  = nt * 16 + n;
        int pv = p > 288 ? 288 : p;     // clamp dead lanes of last tile
        int pi = pv / 17, pj = pv - pi * 17;
        int base = (pi * PS + pj) * 128 + g16;

        f32x4 acc = {0.f, 0.f, 0.f, 0.f};
#pragma unroll
        for (int d = 0; d < 9; ++d) {
            int off = base + DOFF[d] * 128;
            f16x8 bfA = *(const f16x8*)(frq + swz(off));
            f16x8 bfB = *(const f16x8*)(frq + swz(off + 64));
            f16x8 wfA = *(const f16x8*)(wbase + (2 * d) * 1024);
            f16x8 wfB = *(const f16x8*)(wbase + (2 * d + 1) * 1024);
            acc = __builtin_amdgcn_mfma_f32_16x16x32_f16(wfA, bfA, acc, 0, 0, 0);
            acc = __builtin_amdgcn_mfma_f32_16x16x32_f16(wfB, bfB, acc, 0, 0, 0);
        }

        float part = 0.f;
#pragma unroll
        for (int r = 0; r < 4; ++r)
            part = fmaf(w2v[r], fmaxf(acc[r] + b1v[r], 0.f), part);
        part += __shfl_xor(part, 16);
        part += __shfl_xor(part, 32);

        if (lane < 16 && p < 289) {
            float pre = part + b2v;
            float s = 1.f / (1.f + expf(-pre));
            s = fminf(fmaxf(s, 0.05f), 0.95f);
            out[((size_t)(b * 510 + h0 + pi)) * 510 + (w0 + pj)] = s;
        }
    }
}

extern "C" void kernel_launch(void* const* d_in, const int* in_sizes, int n_in,
                              void* d_out, int out_size, void* d_ws, size_t ws_size,
                              hipStream_t stream) {
    const float* x       = (const float*)d_in[0];
    const float* sobel_w = (const float*)d_in[1];
    const float* w1      = (const float*)d_in[2];
    const float* b1      = (const float*)d_in[3];
    const float* w2      = (const float*)d_in[4];
    const float* b2      = (const float*)d_in[5];
    float* out = (float*)d_out;
    unsigned short* wtab = (unsigned short*)d_ws;   // 18*64*16 = 18432 B

    prep_w1<<<dim3(18), dim3(64), 0, stream>>>(w1, wtab);
    fasa_mfma<<<dim3(3600), dim3(NT), 0, stream>>>(x, sobel_w, wtab, b1, w2, b2, out);
}